// Round 2
// 567.607 us; speedup vs baseline: 1.0353x; 1.0353x over previous
//
#include <hip/hip_runtime.h>
#include <math.h>

#define B_ 128
#define S_ 1024
#define D_ 512
#define H_ 512

typedef _Float16 f16x2 __attribute__((ext_vector_type(2)));
typedef _Float16 f16x4 __attribute__((ext_vector_type(4)));
typedef _Float16 f16x8 __attribute__((ext_vector_type(8)));
typedef float    f32x4 __attribute__((ext_vector_type(4)));

// ---------------------------------------------------------------------------
__global__ void zero_k(float* __restrict__ p, int n) {
    int i = blockIdx.x * 256 + threadIdx.x;
    if (i < n) p[i] = 0.f;
}

// new path: zero att, init hidden[b,h] = b_ctx[h] (cbar2 atomically accumulates)
__global__ void init2_k(float* __restrict__ att, float* __restrict__ hidden,
                        const float* __restrict__ bc) {
    int i = blockIdx.x * 256 + threadIdx.x;
    if (i < B_ * S_) att[i] = 0.f;
    else if (i < B_ * S_ + B_ * H_) {
        int j = i - B_ * S_;
        hidden[j] = bc[j & (H_ - 1)];
    }
}

// ---------------------------------------------------------------------------
// out[b,h] = dot(X[b,:], W[h,:]) + bias[h]   (X:[B,D], W:[H,D], D=512)
__global__ __launch_bounds__(256) void linear_k(const float* __restrict__ X,
                                                const float* __restrict__ W,
                                                const float* __restrict__ bias,
                                                float* __restrict__ out) {
    int idx = blockIdx.x * 256 + threadIdx.x;
    int b = idx >> 9;
    int h = idx & 511;
    const float4* x = (const float4*)(X + (size_t)b * D_);
    const float4* w = (const float4*)(W + (size_t)h * D_);
    float s = 0.f;
#pragma unroll 8
    for (int k = 0; k < D_ / 4; ++k) {
        float4 xv = x[k], wv = w[k];
        s = fmaf(xv.x, wv.x, s);
        s = fmaf(xv.y, wv.y, s);
        s = fmaf(xv.z, wv.z, s);
        s = fmaf(xv.w, wv.w, s);
    }
    out[idx] = s + bias[h];
}

// ---------------------------------------------------------------------------
__device__ inline f16x4 cvt4(float4 v) {   // RTN casts (precision identical to prev)
    f16x4 r;
    r[0] = (_Float16)v.x; r[1] = (_Float16)v.y;
    r[2] = (_Float16)v.z; r[3] = (_Float16)v.w;
    return r;
}

// fast tanh: 1 - 2/(e^{2x}+1); exact limits at +/-inf
__device__ inline float fast_tanh(float x) {
    float e = __expf(2.f * x);
    return 1.f - 2.f / (e + 1.f);
}

// ---------------------------------------------------------------------------
// Score GEMM, fp16 MFMA. Grid (s=8, h=4, b): lid = s + 8h + 32b, so lid%8 = s-tile
// -> the 4 h-blocks sharing a 256KB ctx s-tile land on the SAME XCD L2,
//    consecutively dispatched (reuse 4x instead of measured 2x).
// Per (s-blk, h-blk, b): 128x128 tile of ctxp[h,s] = W_ctx[h,:]·context[b,s,:]
// Epilogue: att[b,s] += sum_h V[h]*tanh(inp[b,h]+b_ctx[h]+ctxp)  (atomicAdd)
// If WCTX: also store ctxp (no bias) as f16 [B,S,H] for the cbar2 GEMV.
template <bool WCTX>
__global__ __launch_bounds__(256) void score_mfma(const float* __restrict__ ctx,
                                                  const float* __restrict__ Wc,
                                                  const float* __restrict__ bc,
                                                  const float* __restrict__ Vv,
                                                  const float* __restrict__ inp,
                                                  float* __restrict__ att,
                                                  _Float16* __restrict__ ctxp) {
    // row-major [row][k] fp16 tiles, stride 40 (80 B) -> 16B-aligned b128 frags
    __shared__ __align__(16) _Float16 Ah[128][40];
    __shared__ __align__(16) _Float16 Bh[128][40];
    __shared__ float red[8][128];

    const int tid = threadIdx.x;
    const int s0 = blockIdx.x * 128;   // s-blk fastest (XCD-aligned reuse)
    const int h0 = blockIdx.y * 128;
    const int b  = blockIdx.z;

    // staging: thread covers rows rb+{0,32,64,96}, float4-group grp (k-cols grp*4..+3)
    const int rb  = tid >> 3;   // 0..31
    const int grp = tid & 7;    // 0..7

    const int wave = tid >> 6;
    const int lane = tid & 63;
    const int wm = wave >> 1, wn = wave & 1;   // 2x2 wave grid (h x s)
    const int l15 = lane & 15, quad = lane >> 4;

    const float* Abase = Wc  + (size_t)(h0 + rb) * D_ + grp * 4;
    const float* Bbase = ctx + ((size_t)b * S_ + s0 + rb) * D_ + grp * 4;

    f32x4 acc[4][4];
#pragma unroll
    for (int mi = 0; mi < 4; ++mi)
#pragma unroll
        for (int ni = 0; ni < 4; ++ni) acc[mi][ni] = (f32x4){0.f, 0.f, 0.f, 0.f};

    float4 ra[4], rbv[4];
#pragma unroll
    for (int i = 0; i < 4; ++i) {
        ra[i]  = *(const float4*)(Abase + (size_t)(32 * i) * D_);
        rbv[i] = *(const float4*)(Bbase + (size_t)(32 * i) * D_);
    }

    for (int k0 = 0; k0 < D_; k0 += 32) {
        __syncthreads();   // previous iteration's fragment reads complete
#pragma unroll
        for (int i = 0; i < 4; ++i) {
            const int row = rb + 32 * i;
            *(f16x4*)&Ah[row][grp * 4] = cvt4(ra[i]);
            *(f16x4*)&Bh[row][grp * 4] = cvt4(rbv[i]);
        }
        __syncthreads();
        if (k0 + 32 < D_) {
#pragma unroll
            for (int i = 0; i < 4; ++i) {
                ra[i]  = *(const float4*)(Abase + (size_t)(32 * i) * D_ + k0 + 32);
                rbv[i] = *(const float4*)(Bbase + (size_t)(32 * i) * D_ + k0 + 32);
            }
        }
        // fragments: A[m=l15][k=quad*8+j], B[k=quad*8+j][n=l15]
        f16x8 bhf[4];
#pragma unroll
        for (int ni = 0; ni < 4; ++ni)
            bhf[ni] = *(const f16x8*)&Bh[wn * 64 + ni * 16 + l15][quad * 8];
#pragma unroll
        for (int mi = 0; mi < 4; ++mi) {
            f16x8 ah = *(const f16x8*)&Ah[wm * 64 + mi * 16 + l15][quad * 8];
#pragma unroll
            for (int ni = 0; ni < 4; ++ni)
                acc[mi][ni] = __builtin_amdgcn_mfma_f32_16x16x32_f16(ah, bhf[ni], acc[mi][ni], 0, 0, 0);
        }
    }

    // C/D layout: col(s)=l15, row(h)=quad*4+reg
    // --- optional ctxp store (f16 [B,S,H]): issue stores first, overlap w/ tanh ---
    if (WCTX) {
#pragma unroll
        for (int ni = 0; ni < 4; ++ni) {
            const size_t srow = ((size_t)b * S_ + s0 + wn * 64 + ni * 16 + l15) * H_;
#pragma unroll
            for (int mi = 0; mi < 4; ++mi) {
                f16x4 v;
                v[0] = (_Float16)acc[mi][ni][0];
                v[1] = (_Float16)acc[mi][ni][1];
                v[2] = (_Float16)acc[mi][ni][2];
                v[3] = (_Float16)acc[mi][ni][3];
                *(f16x4*)(ctxp + srow + h0 + wm * 64 + mi * 16 + quad * 4) = v;
            }
        }
    }

    // --- att epilogue ---
    float p[4] = {0.f, 0.f, 0.f, 0.f};
#pragma unroll
    for (int mi = 0; mi < 4; ++mi) {
#pragma unroll
        for (int r = 0; r < 4; ++r) {
            const int h = h0 + wm * 64 + mi * 16 + quad * 4 + r;
            const float c  = inp[(size_t)b * H_ + h] + bc[h];
            const float vh = Vv[h];
#pragma unroll
            for (int ni = 0; ni < 4; ++ni)
                p[ni] = fmaf(vh, fast_tanh(c + acc[mi][ni][r]), p[ni]);
        }
    }
    const int cid = wm * 4 + quad;   // 8 h-contributors per s column
#pragma unroll
    for (int ni = 0; ni < 4; ++ni)
        red[cid][wn * 64 + ni * 16 + l15] = p[ni];
    __syncthreads();
    if (tid < 128) {
        float s = 0.f;
#pragma unroll
        for (int g = 0; g < 8; ++g) s += red[g][tid];
        atomicAdd(att + (size_t)b * S_ + s0 + tid, s);
    }
}

// ---------------------------------------------------------------------------
__global__ __launch_bounds__(256) void softmax_k(const float* __restrict__ att,
                                                 const int* __restrict__ mask,
                                                 float* __restrict__ alpha) {
    const int b = blockIdx.x;
    const int t = threadIdx.x;
    __shared__ float sm[256];
    float v[4];
    float mx = -INFINITY;
#pragma unroll
    for (int i = 0; i < 4; ++i) {
        int s = t + i * 256;
        float a = att[(size_t)b * S_ + s];
        int mk = mask[(size_t)b * S_ + s];
        v[i] = mk ? -INFINITY : a;
        mx = fmaxf(mx, v[i]);
    }
    sm[t] = mx;
    __syncthreads();
    for (int off = 128; off > 0; off >>= 1) {
        if (t < off) sm[t] = fmaxf(sm[t], sm[t + off]);
        __syncthreads();
    }
    mx = sm[0];
    __syncthreads();
    float e[4];
    float sum = 0.f;
#pragma unroll
    for (int i = 0; i < 4; ++i) {
        e[i] = expf(v[i] - mx);
        sum += e[i];
    }
    sm[t] = sum;
    __syncthreads();
    for (int off = 128; off > 0; off >>= 1) {
        if (t < off) sm[t] += sm[t + off];
        __syncthreads();
    }
    float inv = 1.f / sm[0];
#pragma unroll
    for (int i = 0; i < 4; ++i) alpha[(size_t)b * S_ + t + i * 256] = e[i] * inv;
}

// ---------------------------------------------------------------------------
// NEW: hidden[b,h] += sum_{s in chunk} alpha[b,s] * ctxp[b,s,h]  (f16 ctxp)
// grid (8 s-chunks, B). Wave-per-row: lane reads f16x8 (16B) -> fully coalesced.
__global__ __launch_bounds__(256) void cbar2_k(const _Float16* __restrict__ ctxp,
                                               const float* __restrict__ alpha,
                                               float* __restrict__ hidden) {
    const int b  = blockIdx.y;
    const int s0 = blockIdx.x * 128;
    const int t  = threadIdx.x;
    const int w = t >> 6, lane = t & 63;
    __shared__ float al[128];
    __shared__ float red[3][512];
    if (t < 128) al[t] = alpha[(size_t)b * S_ + s0 + t];
    __syncthreads();
    const _Float16* base = ctxp + ((size_t)b * S_ + s0) * H_ + lane * 8;
    float acc[8] = {0.f, 0.f, 0.f, 0.f, 0.f, 0.f, 0.f, 0.f};
#pragma unroll 4
    for (int s = w; s < 128; s += 4) {
        float a = al[s];
        f16x8 v = *(const f16x8*)(base + (size_t)s * H_);
#pragma unroll
        for (int j = 0; j < 8; ++j) acc[j] = fmaf(a, (float)v[j], acc[j]);
    }
    if (w > 0) {
#pragma unroll
        for (int j = 0; j < 8; ++j) red[w - 1][lane * 8 + j] = acc[j];
    }
    __syncthreads();
    if (w == 0) {
        float* dst = hidden + (size_t)b * H_ + lane * 8;
#pragma unroll
        for (int j = 0; j < 8; ++j)
            atomicAdd(dst + j, acc[j] + red[0][lane * 8 + j] + red[1][lane * 8 + j] + red[2][lane * 8 + j]);
    }
}

// ---------------------------------------------------------------------------
// OLD fallback: cbar[b,:] += sum_{s in chunk} alpha[b,s] * context[b,s,:]
__global__ __launch_bounds__(256) void cbar_k(const float* __restrict__ ctx,
                                              const float* __restrict__ alpha,
                                              float* __restrict__ cbar) {
    const int b = blockIdx.y;
    const int s0 = blockIdx.x * 128;
    const int t = threadIdx.x;
    const int c4 = t & 127;   // float4 column 0..127 (D/4)
    const int sh = t >> 7;    // 0/1
    __shared__ float al[128];
    __shared__ float4 red[128];
    if (t < 128) al[t] = alpha[(size_t)b * S_ + s0 + t];
    __syncthreads();
    const float4* base = (const float4*)(ctx + ((size_t)b * S_ + s0) * D_);
    float4 c = {0.f, 0.f, 0.f, 0.f};
#pragma unroll 4
    for (int s = sh; s < 128; s += 2) {
        float a = al[s];
        float4 x = base[(size_t)s * (D_ / 4) + c4];
        c.x = fmaf(a, x.x, c.x);
        c.y = fmaf(a, x.y, c.y);
        c.z = fmaf(a, x.z, c.z);
        c.w = fmaf(a, x.w, c.w);
    }
    if (sh == 1) red[c4] = c;
    __syncthreads();
    if (sh == 0) {
        float4 o = red[c4];
        float* dst = cbar + (size_t)b * D_ + c4 * 4;
        atomicAdd(dst + 0, c.x + o.x);
        atomicAdd(dst + 1, c.y + o.y);
        atomicAdd(dst + 2, c.z + o.z);
        atomicAdd(dst + 3, c.w + o.w);
    }
}

// ---------------------------------------------------------------------------
extern "C" void kernel_launch(void* const* d_in, const int* in_sizes, int n_in,
                              void* d_out, int out_size, void* d_ws, size_t ws_size,
                              hipStream_t stream) {
    const float* input = (const float*)d_in[0];
    const float* ctx   = (const float*)d_in[1];
    const int*   mask  = (const int*)d_in[2];
    const float* W_in  = (const float*)d_in[3];
    const float* b_in  = (const float*)d_in[4];
    const float* W_ctx = (const float*)d_in[5];
    const float* b_ctx = (const float*)d_in[6];
    const float* V     = (const float*)d_in[7];

    float* hidden = (float*)d_out;
    float* alpha  = (float*)d_out + B_ * H_;

    float* inp  = (float*)d_ws;
    float* att  = inp + B_ * H_;
    float* cbar = att + B_ * S_;
    _Float16* ctxp = (_Float16*)(cbar + B_ * D_);   // offset 1 MiB, 16B-aligned

    const size_t base_bytes = (size_t)(B_ * H_ + B_ * S_ + B_ * D_) * sizeof(float);
    const size_t ctxp_bytes = (size_t)B_ * S_ * H_ * sizeof(_Float16);   // 134 MB
    const bool big = ws_size >= base_bytes + ctxp_bytes;

    dim3 g2(S_ / 128, H_ / 128, B_);   // s fastest -> lid%8 = s-tile (XCD reuse)

    if (big) {
        // --- ctxp path: score stores projected ctx, GEMV replaces cbar+linear ---
        int ni = B_ * S_ + B_ * H_;
        init2_k<<<(ni + 255) / 256, 256, 0, stream>>>(att, hidden, b_ctx);

        linear_k<<<(B_ * H_) / 256, 256, 0, stream>>>(input, W_in, b_in, inp);

        score_mfma<true><<<g2, 256, 0, stream>>>(ctx, W_ctx, b_ctx, V, inp, att, ctxp);

        softmax_k<<<B_, 256, 0, stream>>>(att, mask, alpha);

        dim3 g4(S_ / 128, B_);
        cbar2_k<<<g4, 256, 0, stream>>>(ctxp, alpha, hidden);
    } else {
        // --- fallback: previous verified path (with swizzled score grid) ---
        int nz = B_ * S_ + B_ * D_;
        zero_k<<<(nz + 255) / 256, 256, 0, stream>>>(att, nz);

        linear_k<<<(B_ * H_) / 256, 256, 0, stream>>>(input, W_in, b_in, inp);

        score_mfma<false><<<g2, 256, 0, stream>>>(ctx, W_ctx, b_ctx, V, inp, att, nullptr);

        softmax_k<<<B_, 256, 0, stream>>>(att, mask, alpha);

        dim3 g4(S_ / 128, B_);
        cbar_k<<<g4, 256, 0, stream>>>(ctx, alpha, cbar);

        linear_k<<<(B_ * H_) / 256, 256, 0, stream>>>(cbar, W_ctx, b_ctx, hidden);
    }
}

// Round 3
// 554.032 us; speedup vs baseline: 1.0607x; 1.0245x over previous
//
#include <hip/hip_runtime.h>
#include <math.h>

#define B_ 128
#define S_ 1024
#define D_ 512
#define H_ 512

typedef _Float16 f16x4 __attribute__((ext_vector_type(4)));
typedef _Float16 f16x8 __attribute__((ext_vector_type(8)));
typedef float    f32x4 __attribute__((ext_vector_type(4)));

// ---------------------------------------------------------------------------
__global__ void zero_k(float* __restrict__ p, int n) {
    int i = blockIdx.x * 256 + threadIdx.x;
    if (i < n) p[i] = 0.f;
}

// zero att, init hidden[b,h] = b_ctx[h] (cbar2 atomically accumulates)
__global__ void init2_k(float* __restrict__ att, float* __restrict__ hidden,
                        const float* __restrict__ bc) {
    int i = blockIdx.x * 256 + threadIdx.x;
    if (i < B_ * S_) att[i] = 0.f;
    else if (i < B_ * S_ + B_ * H_) {
        int j = i - B_ * S_;
        hidden[j] = bc[j & (H_ - 1)];
    }
}

// ---------------------------------------------------------------------------
// out[b,h] = dot(X[b,:], W[h,:]) + bias[h]   (X:[B,D], W:[H,D], D=512)
__global__ __launch_bounds__(256) void linear_k(const float* __restrict__ X,
                                                const float* __restrict__ W,
                                                const float* __restrict__ bias,
                                                float* __restrict__ out) {
    int idx = blockIdx.x * 256 + threadIdx.x;
    int b = idx >> 9;
    int h = idx & 511;
    const float4* x = (const float4*)(X + (size_t)b * D_);
    const float4* w = (const float4*)(W + (size_t)h * D_);
    float s = 0.f;
#pragma unroll 8
    for (int k = 0; k < D_ / 4; ++k) {
        float4 xv = x[k], wv = w[k];
        s = fmaf(xv.x, wv.x, s);
        s = fmaf(xv.y, wv.y, s);
        s = fmaf(xv.z, wv.z, s);
        s = fmaf(xv.w, wv.w, s);
    }
    out[idx] = s + bias[h];
}

// ---------------------------------------------------------------------------
__device__ inline f16x8 cvt8(float4 a, float4 b) {   // RTN casts
    f16x8 r;
    r[0] = (_Float16)a.x; r[1] = (_Float16)a.y;
    r[2] = (_Float16)a.z; r[3] = (_Float16)a.w;
    r[4] = (_Float16)b.x; r[5] = (_Float16)b.y;
    r[6] = (_Float16)b.z; r[7] = (_Float16)b.w;
    return r;
}

// fast tanh: 1 - 2/(e^{2x}+1); exact limits at +/-inf
__device__ inline float fast_tanh(float x) {
    float e = __expf(2.f * x);
    return 1.f - 2.f / (e + 1.f);
}

// ---------------------------------------------------------------------------
// Score GEMM, fp16 MFMA, double-buffered LDS, ONE barrier per K-step.
// LDS tiles [128][32] fp16 with 16B-granule XOR swizzle: granule g of row r
// stored at granule (g ^ (r&3)) -> both ds_write_b128 staging and ds_read_b128
// fragment reads are minimum-cycle (even rows banks 0-15, odd rows 16-31).
// Grid (s=8, h=4, b): lid%8 = s-tile -> 4 h-blocks share ctx tile on one XCD L2.
// Epilogue: att[b,s] += sum_h V[h]*tanh(inp[b,h]+b_ctx[h]+ctxp)  (atomicAdd)
// If WCTX: also store ctxp (no bias) as f16 [B,S,H] for the cbar2 GEMV.
template <bool WCTX>
__global__ __launch_bounds__(256) void score_mfma(const float* __restrict__ ctx,
                                                  const float* __restrict__ Wc,
                                                  const float* __restrict__ bc,
                                                  const float* __restrict__ Vv,
                                                  const float* __restrict__ inp,
                                                  float* __restrict__ att,
                                                  _Float16* __restrict__ ctxp) {
    __shared__ __align__(16) _Float16 Ah[2][128][32];
    __shared__ __align__(16) _Float16 Bh[2][128][32];
    __shared__ float red[8][128];

    const int tid = threadIdx.x;
    const int s0 = blockIdx.x * 128;   // s-blk fastest (XCD-aligned reuse)
    const int h0 = blockIdx.y * 128;
    const int b  = blockIdx.z;

    // staging: thread -> rows r0, r0+64 of both tiles, k-granule kg (8 halves)
    const int r0  = tid >> 2;          // 0..63
    const int kg  = tid & 3;           // 0..3
    const int swz = ((kg ^ (r0 & 3)) << 3);   // swizzled half-offset within row

    const int wave = tid >> 6;
    const int lane = tid & 63;
    const int wm = wave >> 1, wn = wave & 1;   // 2x2 wave grid (h x s)
    const int l15 = lane & 15, quad = lane >> 4;
    const int rdsw = ((quad ^ (l15 & 3)) << 3);   // read-side swizzle (row&3 == l15&3)

    const float* Arow0 = Wc  + (size_t)(h0 + r0) * D_ + kg * 8;
    const float* Arow1 = Arow0 + (size_t)64 * D_;
    const float* Brow0 = ctx + ((size_t)b * S_ + s0 + r0) * D_ + kg * 8;
    const float* Brow1 = Brow0 + (size_t)64 * D_;

    f32x4 acc[4][4];
#pragma unroll
    for (int mi = 0; mi < 4; ++mi)
#pragma unroll
        for (int ni = 0; ni < 4; ++ni) acc[mi][ni] = (f32x4){0.f, 0.f, 0.f, 0.f};

    float4 A0a, A0b, A1a, A1b, B0a, B0b, B1a, B1b;

#define LOADS(step) do { const int kk_ = (step) * 32;                               \
    A0a = *(const float4*)(Arow0 + kk_); A0b = *(const float4*)(Arow0 + kk_ + 4);   \
    A1a = *(const float4*)(Arow1 + kk_); A1b = *(const float4*)(Arow1 + kk_ + 4);   \
    B0a = *(const float4*)(Brow0 + kk_); B0b = *(const float4*)(Brow0 + kk_ + 4);   \
    B1a = *(const float4*)(Brow1 + kk_); B1b = *(const float4*)(Brow1 + kk_ + 4); } while (0)

#define WRITE(bf) do {                                                              \
    *(f16x8*)&Ah[bf][r0][swz]      = cvt8(A0a, A0b);                                \
    *(f16x8*)&Ah[bf][r0 + 64][swz] = cvt8(A1a, A1b);                                \
    *(f16x8*)&Bh[bf][r0][swz]      = cvt8(B0a, B0b);                                \
    *(f16x8*)&Bh[bf][r0 + 64][swz] = cvt8(B1a, B1b); } while (0)

#define COMPUTE(bf) do {                                                            \
    f16x8 bhf_[4];                                                                  \
    _Pragma("unroll")                                                               \
    for (int ni = 0; ni < 4; ++ni)                                                  \
        bhf_[ni] = *(const f16x8*)&Bh[bf][wn * 64 + ni * 16 + l15][rdsw];           \
    _Pragma("unroll")                                                               \
    for (int mi = 0; mi < 4; ++mi) {                                                \
        f16x8 ah_ = *(const f16x8*)&Ah[bf][wm * 64 + mi * 16 + l15][rdsw];          \
        _Pragma("unroll")                                                           \
        for (int ni = 0; ni < 4; ++ni)                                              \
            acc[mi][ni] = __builtin_amdgcn_mfma_f32_16x16x32_f16(ah_, bhf_[ni],     \
                                                                 acc[mi][ni], 0, 0, 0); \
    } } while (0)

    // prologue: step0 -> buf0, issue step1 loads
    LOADS(0);
    WRITE(0);
    LOADS(1);
    __syncthreads();

    // steady state: 1 barrier per K-step; write next-step tile into the idle
    // buffer while this step's MFMAs run; loads issued one step ahead.
    for (int it = 0; it < 16; it += 2) {
        COMPUTE(0);                    // step it      (reads buf0)
        WRITE(1);                      // step it+1    (writes buf1; vmcnt auto)
        if (it + 2 < 16) LOADS(it + 2);
        __syncthreads();
        COMPUTE(1);                    // step it+1    (reads buf1)
        if (it + 2 < 16) WRITE(0);     // step it+2
        if (it + 3 < 16) LOADS(it + 3);
        __syncthreads();
    }
#undef LOADS
#undef WRITE
#undef COMPUTE

    // C/D layout: col(s)=l15, row(h)=quad*4+reg
    // --- optional ctxp store (f16 [B,S,H]) ---
    if (WCTX) {
#pragma unroll
        for (int ni = 0; ni < 4; ++ni) {
            const size_t srow = ((size_t)b * S_ + s0 + wn * 64 + ni * 16 + l15) * H_;
#pragma unroll
            for (int mi = 0; mi < 4; ++mi) {
                f16x4 v;
                v[0] = (_Float16)acc[mi][ni][0];
                v[1] = (_Float16)acc[mi][ni][1];
                v[2] = (_Float16)acc[mi][ni][2];
                v[3] = (_Float16)acc[mi][ni][3];
                *(f16x4*)(ctxp + srow + h0 + wm * 64 + mi * 16 + quad * 4) = v;
            }
        }
    }

    // --- att epilogue ---
    float p[4] = {0.f, 0.f, 0.f, 0.f};
#pragma unroll
    for (int mi = 0; mi < 4; ++mi) {
#pragma unroll
        for (int r = 0; r < 4; ++r) {
            const int h = h0 + wm * 64 + mi * 16 + quad * 4 + r;
            const float c  = inp[(size_t)b * H_ + h] + bc[h];
            const float vh = Vv[h];
#pragma unroll
            for (int ni = 0; ni < 4; ++ni)
                p[ni] = fmaf(vh, fast_tanh(c + acc[mi][ni][r]), p[ni]);
        }
    }
    const int cid = wm * 4 + quad;   // 8 h-contributors per s column
#pragma unroll
    for (int ni = 0; ni < 4; ++ni)
        red[cid][wn * 64 + ni * 16 + l15] = p[ni];
    __syncthreads();
    if (tid < 128) {
        float s = 0.f;
#pragma unroll
        for (int g = 0; g < 8; ++g) s += red[g][tid];
        atomicAdd(att + (size_t)b * S_ + s0 + tid, s);
    }
}

// ---------------------------------------------------------------------------
__global__ __launch_bounds__(256) void softmax_k(const float* __restrict__ att,
                                                 const int* __restrict__ mask,
                                                 float* __restrict__ alpha) {
    const int b = blockIdx.x;
    const int t = threadIdx.x;
    __shared__ float sm[256];
    float v[4];
    float mx = -INFINITY;
#pragma unroll
    for (int i = 0; i < 4; ++i) {
        int s = t + i * 256;
        float a = att[(size_t)b * S_ + s];
        int mk = mask[(size_t)b * S_ + s];
        v[i] = mk ? -INFINITY : a;
        mx = fmaxf(mx, v[i]);
    }
    sm[t] = mx;
    __syncthreads();
    for (int off = 128; off > 0; off >>= 1) {
        if (t < off) sm[t] = fmaxf(sm[t], sm[t + off]);
        __syncthreads();
    }
    mx = sm[0];
    __syncthreads();
    float e[4];
    float sum = 0.f;
#pragma unroll
    for (int i = 0; i < 4; ++i) {
        e[i] = expf(v[i] - mx);
        sum += e[i];
    }
    sm[t] = sum;
    __syncthreads();
    for (int off = 128; off > 0; off >>= 1) {
        if (t < off) sm[t] += sm[t + off];
        __syncthreads();
    }
    float inv = 1.f / sm[0];
#pragma unroll
    for (int i = 0; i < 4; ++i) alpha[(size_t)b * S_ + t + i * 256] = e[i] * inv;
}

// ---------------------------------------------------------------------------
// hidden[b,h] += sum_{s in chunk} alpha[b,s] * ctxp[b,s,h]  (f16 ctxp)
__global__ __launch_bounds__(256) void cbar2_k(const _Float16* __restrict__ ctxp,
                                               const float* __restrict__ alpha,
                                               float* __restrict__ hidden) {
    const int b  = blockIdx.y;
    const int s0 = blockIdx.x * 128;
    const int t  = threadIdx.x;
    const int w = t >> 6, lane = t & 63;
    __shared__ float al[128];
    __shared__ float red[3][512];
    if (t < 128) al[t] = alpha[(size_t)b * S_ + s0 + t];
    __syncthreads();
    const _Float16* base = ctxp + ((size_t)b * S_ + s0) * H_ + lane * 8;
    float acc[8] = {0.f, 0.f, 0.f, 0.f, 0.f, 0.f, 0.f, 0.f};
#pragma unroll 4
    for (int s = w; s < 128; s += 4) {
        float a = al[s];
        f16x8 v = *(const f16x8*)(base + (size_t)s * H_);
#pragma unroll
        for (int j = 0; j < 8; ++j) acc[j] = fmaf(a, (float)v[j], acc[j]);
    }
    if (w > 0) {
#pragma unroll
        for (int j = 0; j < 8; ++j) red[w - 1][lane * 8 + j] = acc[j];
    }
    __syncthreads();
    if (w == 0) {
        float* dst = hidden + (size_t)b * H_ + lane * 8;
#pragma unroll
        for (int j = 0; j < 8; ++j)
            atomicAdd(dst + j, acc[j] + red[0][lane * 8 + j] + red[1][lane * 8 + j] + red[2][lane * 8 + j]);
    }
}

// ---------------------------------------------------------------------------
// fallback: cbar[b,:] += sum_{s in chunk} alpha[b,s] * context[b,s,:]
__global__ __launch_bounds__(256) void cbar_k(const float* __restrict__ ctx,
                                              const float* __restrict__ alpha,
                                              float* __restrict__ cbar) {
    const int b = blockIdx.y;
    const int s0 = blockIdx.x * 128;
    const int t = threadIdx.x;
    const int c4 = t & 127;
    const int sh = t >> 7;
    __shared__ float al[128];
    __shared__ float4 red[128];
    if (t < 128) al[t] = alpha[(size_t)b * S_ + s0 + t];
    __syncthreads();
    const float4* base = (const float4*)(ctx + ((size_t)b * S_ + s0) * D_);
    float4 c = {0.f, 0.f, 0.f, 0.f};
#pragma unroll 4
    for (int s = sh; s < 128; s += 2) {
        float a = al[s];
        float4 x = base[(size_t)s * (D_ / 4) + c4];
        c.x = fmaf(a, x.x, c.x);
        c.y = fmaf(a, x.y, c.y);
        c.z = fmaf(a, x.z, c.z);
        c.w = fmaf(a, x.w, c.w);
    }
    if (sh == 1) red[c4] = c;
    __syncthreads();
    if (sh == 0) {
        float4 o = red[c4];
        float* dst = cbar + (size_t)b * D_ + c4 * 4;
        atomicAdd(dst + 0, c.x + o.x);
        atomicAdd(dst + 1, c.y + o.y);
        atomicAdd(dst + 2, c.z + o.z);
        atomicAdd(dst + 3, c.w + o.w);
    }
}

// ---------------------------------------------------------------------------
extern "C" void kernel_launch(void* const* d_in, const int* in_sizes, int n_in,
                              void* d_out, int out_size, void* d_ws, size_t ws_size,
                              hipStream_t stream) {
    const float* input = (const float*)d_in[0];
    const float* ctx   = (const float*)d_in[1];
    const int*   mask  = (const int*)d_in[2];
    const float* W_in  = (const float*)d_in[3];
    const float* b_in  = (const float*)d_in[4];
    const float* W_ctx = (const float*)d_in[5];
    const float* b_ctx = (const float*)d_in[6];
    const float* V     = (const float*)d_in[7];

    float* hidden = (float*)d_out;
    float* alpha  = (float*)d_out + B_ * H_;

    float* inp  = (float*)d_ws;
    float* att  = inp + B_ * H_;
    float* cbar = att + B_ * S_;
    _Float16* ctxp = (_Float16*)(cbar + B_ * D_);   // offset 1 MiB, 16B-aligned

    const size_t base_bytes = (size_t)(B_ * H_ + B_ * S_ + B_ * D_) * sizeof(float);
    const size_t ctxp_bytes = (size_t)B_ * S_ * H_ * sizeof(_Float16);   // 134 MB
    const bool big = ws_size >= base_bytes + ctxp_bytes;

    dim3 g2(S_ / 128, H_ / 128, B_);   // s fastest -> lid%8 = s-tile (XCD reuse)

    if (big) {
        int ni = B_ * S_ + B_ * H_;
        init2_k<<<(ni + 255) / 256, 256, 0, stream>>>(att, hidden, b_ctx);

        linear_k<<<(B_ * H_) / 256, 256, 0, stream>>>(input, W_in, b_in, inp);

        score_mfma<true><<<g2, 256, 0, stream>>>(ctx, W_ctx, b_ctx, V, inp, att, ctxp);

        softmax_k<<<B_, 256, 0, stream>>>(att, mask, alpha);

        dim3 g4(S_ / 128, B_);
        cbar2_k<<<g4, 256, 0, stream>>>(ctxp, alpha, hidden);
    } else {
        int nz = B_ * S_ + B_ * D_;
        zero_k<<<(nz + 255) / 256, 256, 0, stream>>>(att, nz);

        linear_k<<<(B_ * H_) / 256, 256, 0, stream>>>(input, W_in, b_in, inp);

        score_mfma<false><<<g2, 256, 0, stream>>>(ctx, W_ctx, b_ctx, V, inp, att, nullptr);

        softmax_k<<<B_, 256, 0, stream>>>(att, mask, alpha);

        dim3 g4(S_ / 128, B_);
        cbar_k<<<g4, 256, 0, stream>>>(ctx, alpha, cbar);

        linear_k<<<(B_ * H_) / 256, 256, 0, stream>>>(cbar, W_ctx, b_ctx, hidden);
    }
}